// Round 4
// baseline (65.157 us; speedup 1.0000x reference)
//
#include <hip/hip_runtime.h>
#include <hip/hip_bf16.h>

// TT embedding: vocab 65536, dim 1024, rank 16.
// out[v,d] = sum_{r1..r4} c0[0,i0,r1] c1[r1,i1,r2] c2[r2,i2,r3] c3[r3,i3,r4] c4[r4,i4,0]
//   i0=v>>11, i1=(v>>6)&31, i2=(v>>1)&31, i3=(v&1)*16+(d>>6), i4=d&63
//
// R3 lesson: latency-bound (VALUBusy 14%, occ 21%): grid gave exactly 4
// blocks/CU (no refill slack) and unroll-1 g-loop had zero ILP.
// R4: grid 2048 (block pair shares 16 tokens; stages 1-3 computed
// redundantly, stage 4 split 8+8 tokens), ds_read_b128 w4 reads, unroll 2.

#define G 16

__global__ __launch_bounds__(256) void tt_embed_kernel(
    const float* __restrict__ c0,   // 32*16
    const float* __restrict__ c1,   // 16*32*16
    const float* __restrict__ c2,   // 16*32*16
    const float* __restrict__ c3,   // 16*32*16
    const float* __restrict__ c4,   // 16*64
    const int*   __restrict__ idx,  // n_tokens
    float*       __restrict__ out,  // n_tokens x 1024
    int n_tokens)
{
    const int t = threadIdx.x;
    const int base = (blockIdx.x >> 1) * G;   // token base of the block PAIR

    __shared__ float w2[G][16];
    __shared__ float w3[G][16];
    __shared__ float w4[G][16][20];   // pad to 20 floats/row; rows 16B-aligned

    // ---- Stage 1: w2[g][r2] = sum_r1 c0[i0,r1] * c1[r1,i1,r2]
    {
        const int g = t >> 4, r2 = t & 15;
        const int token = base + g;
        const int v = (token < n_tokens) ? idx[token] : 0;
        const int i0 = (v >> 11) & 31;
        const int i1 = (v >> 6) & 31;
        float acc = 0.f;
        #pragma unroll
        for (int r1 = 0; r1 < 16; ++r1)
            acc = fmaf(c0[i0 * 16 + r1], c1[(r1 * 32 + i1) * 16 + r2], acc);
        w2[g][r2] = acc;
    }
    __syncthreads();

    // ---- Stage 2: w3[g][r3] = sum_r2 w2[g][r2] * c2[r2,i2,r3]
    {
        const int g = t >> 4, r3 = t & 15;
        const int token = base + g;
        const int v = (token < n_tokens) ? idx[token] : 0;
        const int i2 = (v >> 1) & 31;
        float acc = 0.f;
        #pragma unroll
        for (int r2 = 0; r2 < 16; ++r2)
            acc = fmaf(w2[g][r2], c2[(r2 * 32 + i2) * 16 + r3], acc);
        w3[g][r3] = acc;
    }
    __syncthreads();

    // ---- Stage 3: w4[g][d1][r4] = sum_r3 w3[g][r3] * c3[r3, i3, r4]
    {
        const int g = t >> 4, d1 = t & 15;
        const int token = base + g;
        const int v = (token < n_tokens) ? idx[token] : 0;
        const int i3 = ((v & 1) << 4) + d1;
        float4 a0 = {0,0,0,0}, a1 = {0,0,0,0}, a2 = {0,0,0,0}, a3 = {0,0,0,0};
        #pragma unroll
        for (int r3 = 0; r3 < 16; ++r3) {
            const float w = w3[g][r3];
            const float4* row = (const float4*)(c3 + (r3 * 32 + i3) * 16);
            float4 b0 = row[0], b1 = row[1], b2 = row[2], b3 = row[3];
            a0.x = fmaf(w, b0.x, a0.x); a0.y = fmaf(w, b0.y, a0.y);
            a0.z = fmaf(w, b0.z, a0.z); a0.w = fmaf(w, b0.w, a0.w);
            a1.x = fmaf(w, b1.x, a1.x); a1.y = fmaf(w, b1.y, a1.y);
            a1.z = fmaf(w, b1.z, a1.z); a1.w = fmaf(w, b1.w, a1.w);
            a2.x = fmaf(w, b2.x, a2.x); a2.y = fmaf(w, b2.y, a2.y);
            a2.z = fmaf(w, b2.z, a2.z); a2.w = fmaf(w, b2.w, a2.w);
            a3.x = fmaf(w, b3.x, a3.x); a3.y = fmaf(w, b3.y, a3.y);
            a3.z = fmaf(w, b3.z, a3.z); a3.w = fmaf(w, b3.w, a3.w);
        }
        float4* wrow = (float4*)&w4[g][d1][0];
        wrow[0] = a0; wrow[1] = a1; wrow[2] = a2; wrow[3] = a3;
    }
    __syncthreads();

    // ---- Stage 4: out[token, d] = sum_r4 w4[g][d>>6][r4] * c4[r4, d&63]
    // This block handles 8 of the pair's 16 tokens.
    {
        const int d1  = t >> 4;          // d>>6 for d = t*4
        const int i4b = (t & 15) << 2;   // d&63 base

        float4 c4v[16];                  // 64 VGPRs, reused across 8 tokens
        #pragma unroll
        for (int r4 = 0; r4 < 16; ++r4)
            c4v[r4] = *(const float4*)(c4 + (r4 << 6) + i4b);

        const int g0 = (blockIdx.x & 1) << 3;     // 0 or 8
        float* outp = out + (size_t)(base + g0) * 1024 + (t << 2);

        #pragma unroll 2                 // two independent token chains in flight
        for (int gg = 0; gg < 8; ++gg) {
            const float4* wr = (const float4*)&w4[g0 + gg][d1][0];
            float4 wa = wr[0], wb = wr[1], wc = wr[2], wd = wr[3];

            float4 acc = {0,0,0,0};
            #pragma unroll
            for (int j = 0; j < 4; ++j) {
                const float w0 = (&wa.x)[j], w1 = (&wb.x)[j],
                            w2v = (&wc.x)[j], w3v = (&wd.x)[j];
                acc.x = fmaf(w0, c4v[j].x, acc.x);
                acc.y = fmaf(w0, c4v[j].y, acc.y);
                acc.z = fmaf(w0, c4v[j].z, acc.z);
                acc.w = fmaf(w0, c4v[j].w, acc.w);
                acc.x = fmaf(w1, c4v[4 + j].x, acc.x);
                acc.y = fmaf(w1, c4v[4 + j].y, acc.y);
                acc.z = fmaf(w1, c4v[4 + j].z, acc.z);
                acc.w = fmaf(w1, c4v[4 + j].w, acc.w);
                acc.x = fmaf(w2v, c4v[8 + j].x, acc.x);
                acc.y = fmaf(w2v, c4v[8 + j].y, acc.y);
                acc.z = fmaf(w2v, c4v[8 + j].z, acc.z);
                acc.w = fmaf(w2v, c4v[8 + j].w, acc.w);
                acc.x = fmaf(w3v, c4v[12 + j].x, acc.x);
                acc.y = fmaf(w3v, c4v[12 + j].y, acc.y);
                acc.z = fmaf(w3v, c4v[12 + j].z, acc.z);
                acc.w = fmaf(w3v, c4v[12 + j].w, acc.w);
            }
            *(float4*)(outp + (size_t)gg * 1024) = acc;
        }
    }
}

extern "C" void kernel_launch(void* const* d_in, const int* in_sizes, int n_in,
                              void* d_out, int out_size, void* d_ws, size_t ws_size,
                              hipStream_t stream) {
    const float* c0  = (const float*)d_in[0];
    const float* c1  = (const float*)d_in[1];
    const float* c2  = (const float*)d_in[2];
    const float* c3  = (const float*)d_in[3];
    const float* c4  = (const float*)d_in[4];
    const int*   idx = (const int*)d_in[5];
    float* out = (float*)d_out;

    const int n_tokens = in_sizes[5];              // 8 * 2048 = 16384
    const int grid = ((n_tokens + G - 1) / G) * 2; // 2048
    tt_embed_kernel<<<grid, 256, 0, stream>>>(c0, c1, c2, c3, c4, idx, out, n_tokens);
}

// Round 5
// 47.161 us; speedup vs baseline: 1.3816x; 1.3816x over previous
//
#include <hip/hip_runtime.h>
#include <hip/hip_bf16.h>

// TT embedding: vocab 65536, dim 1024, rank 16.
// out[v,d] = sum_{r1..r4} c0[0,i0,r1] c1[r1,i1,r2] c2[r2,i2,r3] c3[r3,i3,r4] c4[r4,i4,0]
//   i0=v>>11, i1=(v>>6)&31, i2=(v>>1)&31, i3=(v&1)*16+(d>>6), i4=d&63
//
// R4 lesson: fused kernel couples a latency-bound prologue (idx load + 3
// barriered 16x16 stages) to a BW-bound epilogue; occupancy never recovers.
// R5: two-kernel split through d_ws.
//   A: stages 1-3 -> ws planes W[q][m] (q=r4 quad, m=token*16+d1), coalesced.
//   B: out = W @ c4 — pure streaming, no barriers/LDS, fill-kernel regime.

#define TA 16   // tokens per block, kernel A
#define TB 8    // tokens per block, kernel B

__global__ __launch_bounds__(256) void tt_stage123(
    const float* __restrict__ c0, const float* __restrict__ c1,
    const float* __restrict__ c2, const float* __restrict__ c3,
    const int*   __restrict__ idx, float* __restrict__ wsp, int n_tokens)
{
    const int t = threadIdx.x;
    const int base = blockIdx.x * TA;
    const int g = t >> 4, r = t & 15;
    const int token = base + g;
    const int v = (token < n_tokens) ? idx[token] : 0;

    __shared__ float w2[TA][17];
    __shared__ float w3[TA][17];

    // Stage 1: w2[g][r] = sum_r1 c0[i0,r1] * c1[r1,i1,r]
    {
        const int i0 = (v >> 11) & 31;
        const int i1 = (v >> 6) & 31;
        float acc = 0.f;
        #pragma unroll
        for (int r1 = 0; r1 < 16; ++r1)
            acc = fmaf(c0[i0 * 16 + r1], c1[(r1 * 32 + i1) * 16 + r], acc);
        w2[g][r] = acc;
    }
    __syncthreads();

    // Stage 2: w3[g][r] = sum_r2 w2[g][r2] * c2[r2,i2,r]
    {
        const int i2 = (v >> 1) & 31;
        float acc = 0.f;
        #pragma unroll
        for (int r2 = 0; r2 < 16; ++r2)
            acc = fmaf(w2[g][r2], c2[(r2 * 32 + i2) * 16 + r], acc);
        w3[g][r] = acc;
    }
    __syncthreads();

    // Stage 3: w4row[d1=r][r4] = sum_r3 w3[g][r3] * c3[r3, i3, r4]; store to planes
    {
        const int d1 = r;
        const int i3 = ((v & 1) << 4) + d1;
        float4 a0 = {0,0,0,0}, a1 = {0,0,0,0}, a2 = {0,0,0,0}, a3 = {0,0,0,0};
        #pragma unroll
        for (int r3 = 0; r3 < 16; ++r3) {
            const float w = w3[g][r3];
            const float4* row = (const float4*)(c3 + (r3 * 32 + i3) * 16);
            float4 b0 = row[0], b1 = row[1], b2 = row[2], b3 = row[3];
            a0.x = fmaf(w, b0.x, a0.x); a0.y = fmaf(w, b0.y, a0.y);
            a0.z = fmaf(w, b0.z, a0.z); a0.w = fmaf(w, b0.w, a0.w);
            a1.x = fmaf(w, b1.x, a1.x); a1.y = fmaf(w, b1.y, a1.y);
            a1.z = fmaf(w, b1.z, a1.z); a1.w = fmaf(w, b1.w, a1.w);
            a2.x = fmaf(w, b2.x, a2.x); a2.y = fmaf(w, b2.y, a2.y);
            a2.z = fmaf(w, b2.z, a2.z); a2.w = fmaf(w, b2.w, a2.w);
            a3.x = fmaf(w, b3.x, a3.x); a3.y = fmaf(w, b3.y, a3.y);
            a3.z = fmaf(w, b3.z, a3.z); a3.w = fmaf(w, b3.w, a3.w);
        }
        if (token < n_tokens) {
            const int m = (base << 4) + t;         // token*16 + d1, lane-contiguous
            const int plane = n_tokens << 4;       // float4s per plane
            float4* p = (float4*)wsp;
            p[m]             = a0;                 // r4 0..3
            p[plane + m]     = a1;                 // r4 4..7
            p[2 * plane + m] = a2;                 // r4 8..11
            p[3 * plane + m] = a3;                 // r4 12..15
        }
    }
}

__global__ __launch_bounds__(256) void tt_stage4(
    const float* __restrict__ c4, const float* __restrict__ wsp,
    float* __restrict__ out, int n_tokens)
{
    const int t = threadIdx.x;
    const int base = blockIdx.x * TB;
    const int d1  = t >> 4;
    const int i4b = (t & 15) << 2;

    float4 c4v[16];                                // 64 VGPRs, reused over TB tokens
    #pragma unroll
    for (int r4 = 0; r4 < 16; ++r4)
        c4v[r4] = *(const float4*)(c4 + (r4 << 6) + i4b);

    const float4* p = (const float4*)wsp;
    const int plane = n_tokens << 4;
    const int gmax = (n_tokens - base < TB) ? (n_tokens - base) : TB;
    float* outp = out + (size_t)base * 1024 + (t << 2);

    #pragma unroll 2
    for (int gg = 0; gg < gmax; ++gg) {
        const int m = ((base + gg) << 4) + d1;
        float4 wa = p[m], wb = p[plane + m], wc = p[2 * plane + m], wd = p[3 * plane + m];
        float w[16] = {wa.x, wa.y, wa.z, wa.w, wb.x, wb.y, wb.z, wb.w,
                       wc.x, wc.y, wc.z, wc.w, wd.x, wd.y, wd.z, wd.w};
        float4 acc = {0,0,0,0};
        #pragma unroll
        for (int r4 = 0; r4 < 16; ++r4) {          // same summation order as R3 (absmax 0)
            acc.x = fmaf(w[r4], c4v[r4].x, acc.x);
            acc.y = fmaf(w[r4], c4v[r4].y, acc.y);
            acc.z = fmaf(w[r4], c4v[r4].z, acc.z);
            acc.w = fmaf(w[r4], c4v[r4].w, acc.w);
        }
        *(float4*)(outp + (size_t)gg * 1024) = acc;
    }
}

// ---------- Fallback: R3 fused kernel (used only if ws_size too small) ----------
__global__ __launch_bounds__(256) void tt_embed_fused(
    const float* __restrict__ c0, const float* __restrict__ c1,
    const float* __restrict__ c2, const float* __restrict__ c3,
    const float* __restrict__ c4, const int* __restrict__ idx,
    float* __restrict__ out, int n_tokens)
{
    const int t = threadIdx.x;
    const int base = blockIdx.x * 16;
    __shared__ float w2[16][16];
    __shared__ float w3[16][16];
    __shared__ float w4[16][16][20];
    {
        const int g = t >> 4, r2 = t & 15;
        const int token = base + g;
        const int v = (token < n_tokens) ? idx[token] : 0;
        const int i0 = (v >> 11) & 31, i1 = (v >> 6) & 31;
        float acc = 0.f;
        #pragma unroll
        for (int r1 = 0; r1 < 16; ++r1)
            acc = fmaf(c0[i0 * 16 + r1], c1[(r1 * 32 + i1) * 16 + r2], acc);
        w2[g][r2] = acc;
    }
    __syncthreads();
    {
        const int g = t >> 4, r3 = t & 15;
        const int token = base + g;
        const int v = (token < n_tokens) ? idx[token] : 0;
        const int i2 = (v >> 1) & 31;
        float acc = 0.f;
        #pragma unroll
        for (int r2 = 0; r2 < 16; ++r2)
            acc = fmaf(w2[g][r2], c2[(r2 * 32 + i2) * 16 + r3], acc);
        w3[g][r3] = acc;
    }
    __syncthreads();
    {
        const int g = t >> 4, d1 = t & 15;
        const int token = base + g;
        const int v = (token < n_tokens) ? idx[token] : 0;
        const int i3 = ((v & 1) << 4) + d1;
        float4 a0 = {0,0,0,0}, a1 = {0,0,0,0}, a2 = {0,0,0,0}, a3 = {0,0,0,0};
        #pragma unroll
        for (int r3 = 0; r3 < 16; ++r3) {
            const float w = w3[g][r3];
            const float4* row = (const float4*)(c3 + (r3 * 32 + i3) * 16);
            float4 b0 = row[0], b1 = row[1], b2 = row[2], b3 = row[3];
            a0.x = fmaf(w, b0.x, a0.x); a0.y = fmaf(w, b0.y, a0.y);
            a0.z = fmaf(w, b0.z, a0.z); a0.w = fmaf(w, b0.w, a0.w);
            a1.x = fmaf(w, b1.x, a1.x); a1.y = fmaf(w, b1.y, a1.y);
            a1.z = fmaf(w, b1.z, a1.z); a1.w = fmaf(w, b1.w, a1.w);
            a2.x = fmaf(w, b2.x, a2.x); a2.y = fmaf(w, b2.y, a2.y);
            a2.z = fmaf(w, b2.z, a2.z); a2.w = fmaf(w, b2.w, a2.w);
            a3.x = fmaf(w, b3.x, a3.x); a3.y = fmaf(w, b3.y, a3.y);
            a3.z = fmaf(w, b3.z, a3.z); a3.w = fmaf(w, b3.w, a3.w);
        }
        float4* wrow = (float4*)&w4[g][d1][0];
        wrow[0] = a0; wrow[1] = a1; wrow[2] = a2; wrow[3] = a3;
    }
    __syncthreads();
    {
        const int d1 = t >> 4;
        const int i4b = (t & 15) << 2;
        float4 c4v[16];
        #pragma unroll
        for (int r4 = 0; r4 < 16; ++r4)
            c4v[r4] = *(const float4*)(c4 + (r4 << 6) + i4b);
        float* outp = out + (size_t)base * 1024 + (t << 2);
        #pragma unroll 1
        for (int g = 0; g < 16; ++g) {
            const float* wr = &w4[g][d1][0];
            float4 acc = {0,0,0,0};
            #pragma unroll
            for (int r4 = 0; r4 < 16; ++r4) {
                const float wv = wr[r4];
                acc.x = fmaf(wv, c4v[r4].x, acc.x);
                acc.y = fmaf(wv, c4v[r4].y, acc.y);
                acc.z = fmaf(wv, c4v[r4].z, acc.z);
                acc.w = fmaf(wv, c4v[r4].w, acc.w);
            }
            *(float4*)(outp + (size_t)g * 1024) = acc;
        }
    }
}

extern "C" void kernel_launch(void* const* d_in, const int* in_sizes, int n_in,
                              void* d_out, int out_size, void* d_ws, size_t ws_size,
                              hipStream_t stream) {
    const float* c0  = (const float*)d_in[0];
    const float* c1  = (const float*)d_in[1];
    const float* c2  = (const float*)d_in[2];
    const float* c3  = (const float*)d_in[3];
    const float* c4  = (const float*)d_in[4];
    const int*   idx = (const int*)d_in[5];
    float* out = (float*)d_out;

    const int n_tokens = in_sizes[5];                    // 8 * 2048 = 16384
    const size_t ws_needed = (size_t)n_tokens * 1024;    // 16*16 floats/token = 1 KB

    if (ws_size >= ws_needed) {
        float* wsp = (float*)d_ws;
        const int gridA = (n_tokens + TA - 1) / TA;      // 1024
        const int gridB = (n_tokens + TB - 1) / TB;      // 2048
        tt_stage123<<<gridA, 256, 0, stream>>>(c0, c1, c2, c3, idx, wsp, n_tokens);
        tt_stage4<<<gridB, 256, 0, stream>>>(c4, wsp, out, n_tokens);
    } else {
        const int grid = (n_tokens + 15) / 16;
        tt_embed_fused<<<grid, 256, 0, stream>>>(c0, c1, c2, c3, c4, idx, out, n_tokens);
    }
}

// Round 7
// 37.914 us; speedup vs baseline: 1.7185x; 1.2439x over previous
//
#include <hip/hip_runtime.h>
#include <hip/hip_bf16.h>

// TT embedding: vocab 65536, dim 1024, rank 16.
// out[v,d] = sum_{r1..r4} c0[0,i0,r1] c1[r1,i1,r2] c2[r2,i2,r3] c3[r3,i3,r4] c4[r4,i4,0]
//   i0=v>>11, i1=(v>>6)&31, i2=(v>>1)&31, i3=(v&1)*16+(d>>6), i4=d&63
//
// R6 design (retry — R6 failed on a macro-parameter name collision: param `w`
// captured the `.w` member tokens):
//  - stages 1-3 are intra-16-lane-group -> wave-local, ZERO barriers (waves
//    0-1 do them; compiler lgkmcnt handles LDS RAW within a wave).
//  - ONE __syncthreads total.
//  - stage 4: c4 in 64 VGPRs (loads issued pre-barrier by all waves),
//    manual 2-deep register pipeline on w-rows (4x ds_read_b128 broadcast for
//    token g+1 issued before token g's 64-FMA block).
//  - r4 summation order identical to R3 (absmax was 0.0).

#define TA 8

#define STEP(WV, k)                              \
    acc.x = fmaf(WV, c4v[k].x, acc.x);           \
    acc.y = fmaf(WV, c4v[k].y, acc.y);           \
    acc.z = fmaf(WV, c4v[k].z, acc.z);           \
    acc.w = fmaf(WV, c4v[k].w, acc.w);

__global__ __launch_bounds__(256) void tt_embed_kernel(
    const float* __restrict__ c0,   // 32*16
    const float* __restrict__ c1,   // 16*32*16
    const float* __restrict__ c2,   // 16*32*16
    const float* __restrict__ c3,   // 16*32*16
    const float* __restrict__ c4,   // 16*64
    const int*   __restrict__ idx,  // n_tokens
    float*       __restrict__ out,  // n_tokens x 1024
    int n_tokens)
{
    const int t = threadIdx.x;
    const int base = blockIdx.x * TA;

    __shared__ float w4[TA][16][20];   // [token][d1][r4(pad)], rows 16B-aligned
    __shared__ float w2[TA][17];
    __shared__ float w3[TA][17];

    // ---- c4 slice into registers (issued before the stage work; VMEM in
    // flight while waves 0-1 run stages 1-3).
    const int i4b = (t & 15) << 2;   // d&63 base for this thread
    float4 c4v[16];
    #pragma unroll
    for (int r4 = 0; r4 < 16; ++r4)
        c4v[r4] = *(const float4*)(c4 + (r4 << 6) + i4b);

    // ---- Stages 1-3: waves 0-1 only (128 threads = 8 tokens x 16 lanes).
    // All cross-lane traffic stays inside each 16-lane group => wave-local,
    // no __syncthreads needed between stages.
    if (t < 128) {
        const int g = t >> 4, r = t & 15;
        const int token = base + g;
        const int v = (token < n_tokens) ? idx[token] : 0;

        // Stage 1: w2[g][r] = sum_r1 c0[i0,r1] * c1[r1,i1,r]
        {
            const int i0 = (v >> 11) & 31;
            const int i1 = (v >> 6) & 31;
            float acc = 0.f;
            #pragma unroll
            for (int r1 = 0; r1 < 16; ++r1)
                acc = fmaf(c0[i0 * 16 + r1], c1[(r1 * 32 + i1) * 16 + r], acc);
            w2[g][r] = acc;
        }
        // Stage 2: w3[g][r] = sum_r2 w2[g][r2] * c2[r2,i2,r]   (same wave)
        {
            const int i2 = (v >> 1) & 31;
            float acc = 0.f;
            #pragma unroll
            for (int r2 = 0; r2 < 16; ++r2)
                acc = fmaf(w2[g][r2], c2[(r2 * 32 + i2) * 16 + r], acc);
            w3[g][r] = acc;
        }
        // Stage 3: w4[g][d1=r][*] = sum_r3 w3[g][r3] * c3[r3,i3,*] (same wave)
        {
            const int d1 = r;
            const int i3 = ((v & 1) << 4) + d1;
            float4 a0 = {0,0,0,0}, a1 = {0,0,0,0}, a2 = {0,0,0,0}, a3 = {0,0,0,0};
            #pragma unroll
            for (int r3 = 0; r3 < 16; ++r3) {
                const float wv = w3[g][r3];
                const float4* row = (const float4*)(c3 + (r3 * 32 + i3) * 16);
                float4 b0 = row[0], b1 = row[1], b2 = row[2], b3 = row[3];
                a0.x = fmaf(wv, b0.x, a0.x); a0.y = fmaf(wv, b0.y, a0.y);
                a0.z = fmaf(wv, b0.z, a0.z); a0.w = fmaf(wv, b0.w, a0.w);
                a1.x = fmaf(wv, b1.x, a1.x); a1.y = fmaf(wv, b1.y, a1.y);
                a1.z = fmaf(wv, b1.z, a1.z); a1.w = fmaf(wv, b1.w, a1.w);
                a2.x = fmaf(wv, b2.x, a2.x); a2.y = fmaf(wv, b2.y, a2.y);
                a2.z = fmaf(wv, b2.z, a2.z); a2.w = fmaf(wv, b2.w, a2.w);
                a3.x = fmaf(wv, b3.x, a3.x); a3.y = fmaf(wv, b3.y, a3.y);
                a3.z = fmaf(wv, b3.z, a3.z); a3.w = fmaf(wv, b3.w, a3.w);
            }
            float4* wrow = (float4*)&w4[g][d1][0];
            wrow[0] = a0; wrow[1] = a1; wrow[2] = a2; wrow[3] = a3;
        }
    }

    __syncthreads();   // the ONLY barrier

    // ---- Stage 4: out[token, d] = sum_r4 w4[g][d>>6][r4] * c4[r4, d&63]
    // 2-deep manual pipeline: token g+1's w-row LDS reads issue before
    // token g's FMA block.
    {
        const int d1 = t >> 4;

        const float4* wr0 = (const float4*)&w4[0][d1][0];
        float4 wa = wr0[0], wb = wr0[1], wc = wr0[2], wd = wr0[3];

        float* outp = out + (size_t)base * 1024 + (t << 2);

        #pragma unroll
        for (int gg = 0; gg < TA; ++gg) {
            const float4* wrn = (const float4*)&w4[(gg + 1) & (TA - 1)][d1][0];
            float4 na = wrn[0], nb = wrn[1], nc = wrn[2], nd = wrn[3];

            float4 acc = {0,0,0,0};
            STEP(wa.x,  0) STEP(wa.y,  1) STEP(wa.z,  2) STEP(wa.w,  3)
            STEP(wb.x,  4) STEP(wb.y,  5) STEP(wb.z,  6) STEP(wb.w,  7)
            STEP(wc.x,  8) STEP(wc.y,  9) STEP(wc.z, 10) STEP(wc.w, 11)
            STEP(wd.x, 12) STEP(wd.y, 13) STEP(wd.z, 14) STEP(wd.w, 15)

            if (base + gg < n_tokens)
                *(float4*)(outp + (size_t)gg * 1024) = acc;

            wa = na; wb = nb; wc = nc; wd = nd;
        }
    }
}

extern "C" void kernel_launch(void* const* d_in, const int* in_sizes, int n_in,
                              void* d_out, int out_size, void* d_ws, size_t ws_size,
                              hipStream_t stream) {
    const float* c0  = (const float*)d_in[0];
    const float* c1  = (const float*)d_in[1];
    const float* c2  = (const float*)d_in[2];
    const float* c3  = (const float*)d_in[3];
    const float* c4  = (const float*)d_in[4];
    const int*   idx = (const int*)d_in[5];
    float* out = (float*)d_out;

    const int n_tokens = in_sizes[5];             // 8 * 2048 = 16384
    const int grid = (n_tokens + TA - 1) / TA;    // 2048
    tt_embed_kernel<<<grid, 256, 0, stream>>>(c0, c1, c2, c3, c4, idx, out, n_tokens);
}